// Round 1
// baseline (203.498 us; speedup 1.0000x reference)
//
#include <hip/hip_runtime.h>

#define B_ROWS 8192
#define IN_DIM 512
#define OUT_DIM 512
#define NDEG 8                 // DEGREE+1
#define KDIM (IN_DIM * NDEG)   // 4096

typedef short bf16x8 __attribute__((ext_vector_type(8)));
typedef float f32x4  __attribute__((ext_vector_type(4)));

__device__ __forceinline__ unsigned short f2bf(float f) {
  unsigned u = __float_as_uint(f);
  u += 0x7fffu + ((u >> 16) & 1u);   // round-to-nearest-even
  return (unsigned short)(u >> 16);
}

__device__ __forceinline__ void laguerre8(float t, float* L) {
  // k*L_k = (2(k-1)+1+alpha - t)*L_{k-1} - (k-1+alpha)*L_{k-2}, alpha=0.5
  L[0] = 1.0f;
  L[1] = 1.5f - t;
#pragma unroll
  for (int k = 2; k < NDEG; ++k) {
    L[k] = ((2.0f * (float)k - 0.5f - t) * L[k - 1] -
            ((float)k - 0.5f) * L[k - 2]) * (1.0f / (float)k);
  }
}

// ---------------- pass 1: A[b][i*8+d] = bf16(L_d(tanh(x[b][i]))) ----------------
__global__ void basis_kernel(const float* __restrict__ x, unsigned short* __restrict__ A) {
  int idx = blockIdx.x * 256 + threadIdx.x;   // 0 .. 8192*512-1 ; b=idx>>9, i=idx&511
  float t = tanhf(x[idx]);
  float L[NDEG];
  laguerre8(t, L);
  uint4 v;
  v.x = (unsigned)f2bf(L[0]) | ((unsigned)f2bf(L[1]) << 16);
  v.y = (unsigned)f2bf(L[2]) | ((unsigned)f2bf(L[3]) << 16);
  v.z = (unsigned)f2bf(L[4]) | ((unsigned)f2bf(L[5]) << 16);
  v.w = (unsigned)f2bf(L[6]) | ((unsigned)f2bf(L[7]) << 16);
  ((uint4*)A)[idx] = v;   // A row b, 8 contiguous k at i*8
}

// ---------------- pass 2: Bt[o][i*8+d] = bf16(coeffs[i][o][d]) ----------------
__global__ void coeff_kernel(const float* __restrict__ c, unsigned short* __restrict__ Bt) {
  int idx = blockIdx.x * 256 + threadIdx.x;   // i*512 + o
  int i = idx >> 9, o = idx & 511;
  const float4* cp = (const float4*)(c + (size_t)idx * 8);
  float4 c0 = cp[0], c1 = cp[1];
  uint4 v;
  v.x = (unsigned)f2bf(c0.x) | ((unsigned)f2bf(c0.y) << 16);
  v.y = (unsigned)f2bf(c0.z) | ((unsigned)f2bf(c0.w) << 16);
  v.z = (unsigned)f2bf(c1.x) | ((unsigned)f2bf(c1.y) << 16);
  v.w = (unsigned)f2bf(c1.z) | ((unsigned)f2bf(c1.w) << 16);
  ((uint4*)Bt)[o * 512 + i] = v;
}

// ---------------- pass 3: C[8192,512] f32 = A[8192,4096]bf16 @ Bt[512,4096]bf16^T ----
// BM=BN=128, BK=64, 256 threads = 4 waves (2x2), wave tile 64x64,
// reg-prefetch double buffer, padded LDS (stride 72 bf16 = 144 B -> conflict-free).
#define LDT 72

__global__ __launch_bounds__(256) void gemm_kernel(const unsigned short* __restrict__ A,
                                                   const unsigned short* __restrict__ Bt,
                                                   float* __restrict__ C) {
  __shared__ unsigned short As[128 * LDT];
  __shared__ unsigned short Bs[128 * LDT];

  const int tid  = threadIdx.x;
  const int lane = tid & 63;
  const int wave = tid >> 6;
  const int wm = wave >> 1, wn = wave & 1;
  const int bn = blockIdx.x * 128;   // 4 n-blocks
  const int bm = blockIdx.y * 128;   // 64 m-blocks

  const uint4* Ag = (const uint4*)A;   // 8 bf16 per chunk; global row = 512 chunks
  const uint4* Bg = (const uint4*)Bt;

  const int r0 = tid >> 3;        // staging row (per j: +32)
  const int c8 = tid & 7;         // staging k-chunk within row

  uint4 ra[4], rb[4];
#pragma unroll
  for (int j = 0; j < 4; ++j) {
    ra[j] = Ag[(size_t)(bm + r0 + j * 32) * 512 + c8];
    rb[j] = Bg[(size_t)(bn + r0 + j * 32) * 512 + c8];
  }

  f32x4 zero = {0.f, 0.f, 0.f, 0.f};
  f32x4 acc[4][4];
#pragma unroll
  for (int mi = 0; mi < 4; ++mi)
#pragma unroll
    for (int ni = 0; ni < 4; ++ni) acc[mi][ni] = zero;

  const int arow = (lane & 15);        // fragment row/col within 16
  const int kgrp = (lane >> 4) * 8;    // 8 contiguous k per lane

  for (int kt = 0; kt < 64; ++kt) {
    __syncthreads();   // previous compute done, LDS reusable
#pragma unroll
    for (int j = 0; j < 4; ++j) {
      *(uint4*)&As[(r0 + j * 32) * LDT + c8 * 8] = ra[j];
      *(uint4*)&Bs[(r0 + j * 32) * LDT + c8 * 8] = rb[j];
    }
    __syncthreads();   // LDS ready

    if (kt < 63) {     // prefetch next K-tile into regs (hides under MFMA)
#pragma unroll
      for (int j = 0; j < 4; ++j) {
        ra[j] = Ag[(size_t)(bm + r0 + j * 32) * 512 + (kt + 1) * 8 + c8];
        rb[j] = Bg[(size_t)(bn + r0 + j * 32) * 512 + (kt + 1) * 8 + c8];
      }
    }

#pragma unroll
    for (int ks = 0; ks < 2; ++ks) {
      bf16x8 af[4], bfr[4];
#pragma unroll
      for (int mi = 0; mi < 4; ++mi)
        af[mi] = *(const bf16x8*)&As[(wm * 64 + mi * 16 + arow) * LDT + ks * 32 + kgrp];
#pragma unroll
      for (int ni = 0; ni < 4; ++ni)
        bfr[ni] = *(const bf16x8*)&Bs[(wn * 64 + ni * 16 + arow) * LDT + ks * 32 + kgrp];
#pragma unroll
      for (int mi = 0; mi < 4; ++mi)
#pragma unroll
        for (int ni = 0; ni < 4; ++ni)
          acc[mi][ni] = __builtin_amdgcn_mfma_f32_16x16x32_bf16(af[mi], bfr[ni], acc[mi][ni], 0, 0, 0);
    }
  }

  // epilogue: C/D layout col = lane&15, row = (lane>>4)*4 + r  [measured m89/m91]
#pragma unroll
  for (int mi = 0; mi < 4; ++mi) {
    int row = bm + wm * 64 + mi * 16 + ((lane >> 4) << 2);
#pragma unroll
    for (int ni = 0; ni < 4; ++ni) {
      int col = bn + wn * 64 + ni * 16 + (lane & 15);
#pragma unroll
      for (int r = 0; r < 4; ++r)
        C[(size_t)(row + r) * 512 + col] = acc[mi][ni][r];
    }
  }
}

// ---------------- fallback (ws too small): direct f32, correct but slow ----------------
__global__ void naive_kernel(const float* __restrict__ x, const float* __restrict__ c,
                             float* __restrict__ out) {
  __shared__ float bas[IN_DIM * NDEG];   // 16 KB
  int b = blockIdx.x;
  for (int i = threadIdx.x; i < IN_DIM; i += 256) {
    float t = tanhf(x[(size_t)b * IN_DIM + i]);
    float L[NDEG];
    laguerre8(t, L);
#pragma unroll
    for (int d = 0; d < NDEG; ++d) bas[i * NDEG + d] = L[d];
  }
  __syncthreads();
  for (int o = threadIdx.x; o < OUT_DIM; o += 256) {
    float acc = 0.f;
    for (int i = 0; i < IN_DIM; ++i) {
      const float* cp = c + ((size_t)i * OUT_DIM + o) * NDEG;
#pragma unroll
      for (int d = 0; d < NDEG; ++d) acc += bas[i * NDEG + d] * cp[d];
    }
    out[(size_t)b * OUT_DIM + o] = acc;
  }
}

extern "C" void kernel_launch(void* const* d_in, const int* in_sizes, int n_in,
                              void* d_out, int out_size, void* d_ws, size_t ws_size,
                              hipStream_t stream) {
  const float* x    = (const float*)d_in[0];
  const float* coef = (const float*)d_in[1];
  float* out = (float*)d_out;

  const size_t A_BYTES  = (size_t)B_ROWS * KDIM * 2;   // 64 MiB
  const size_t BT_BYTES = (size_t)OUT_DIM * KDIM * 2;  // 4 MiB

  if (ws_size >= A_BYTES + BT_BYTES) {
    unsigned short* A  = (unsigned short*)d_ws;
    unsigned short* Bt = (unsigned short*)((char*)d_ws + A_BYTES);
    basis_kernel<<<(B_ROWS * IN_DIM) / 256, 256, 0, stream>>>(x, A);
    coeff_kernel<<<(IN_DIM * OUT_DIM) / 256, 256, 0, stream>>>(coef, Bt);
    dim3 grid(OUT_DIM / 128, B_ROWS / 128);   // (4, 64) = 256 blocks
    gemm_kernel<<<grid, 256, 0, stream>>>(A, Bt, out);
  } else {
    naive_kernel<<<B_ROWS, 256, 0, stream>>>(x, coef, out);
  }
}

// Round 2
// 120.449 us; speedup vs baseline: 1.6895x; 1.6895x over previous
//
#include <hip/hip_runtime.h>

#define B_ROWS 8192
#define IN_DIM 512
#define OUT_DIM 512
#define NDEG 8                 // DEGREE+1
#define KDIM (IN_DIM * NDEG)   // 4096
#define KSLICES 4
#define NT_SLICE 16            // (KDIM/64)/KSLICES K-tiles per slice
#define LDT 72                 // padded LDS stride (shorts): 144 B -> conflict-free

typedef short bf16x8 __attribute__((ext_vector_type(8)));
typedef float f32x4  __attribute__((ext_vector_type(4)));

__device__ __forceinline__ unsigned short f2bf(float f) {
  unsigned u = __float_as_uint(f);
  u += 0x7fffu + ((u >> 16) & 1u);   // round-to-nearest-even
  return (unsigned short)(u >> 16);
}

__device__ __forceinline__ void laguerre8(float t, float* L) {
  // k*L_k = (2(k-1)+1+alpha - t)*L_{k-1} - (k-1+alpha)*L_{k-2}, alpha=0.5
  L[0] = 1.0f;
  L[1] = 1.5f - t;
#pragma unroll
  for (int k = 2; k < NDEG; ++k) {
    L[k] = ((2.0f * (float)k - 0.5f - t) * L[k - 1] -
            ((float)k - 0.5f) * L[k - 2]) * (1.0f / (float)k);
  }
}

__device__ __forceinline__ uint4 basis_pack(float xv) {
  float L[NDEG];
  laguerre8(tanhf(xv), L);
  uint4 v;
  v.x = (unsigned)f2bf(L[0]) | ((unsigned)f2bf(L[1]) << 16);
  v.y = (unsigned)f2bf(L[2]) | ((unsigned)f2bf(L[3]) << 16);
  v.z = (unsigned)f2bf(L[4]) | ((unsigned)f2bf(L[5]) << 16);
  v.w = (unsigned)f2bf(L[6]) | ((unsigned)f2bf(L[7]) << 16);
  return v;
}

// ---------------- pass 1: Bt[o][i*8+d] = bf16(coeffs[i][o][d]) ----------------
__global__ void coeff_kernel(const float* __restrict__ c, unsigned short* __restrict__ Bt) {
  int idx = blockIdx.x * 256 + threadIdx.x;   // i*512 + o
  int i = idx >> 9, o = idx & 511;
  const float4* cp = (const float4*)(c + (size_t)idx * 8);
  float4 c0 = cp[0], c1 = cp[1];
  uint4 v;
  v.x = (unsigned)f2bf(c0.x) | ((unsigned)f2bf(c0.y) << 16);
  v.y = (unsigned)f2bf(c0.z) | ((unsigned)f2bf(c0.w) << 16);
  v.z = (unsigned)f2bf(c1.x) | ((unsigned)f2bf(c1.y) << 16);
  v.w = (unsigned)f2bf(c1.z) | ((unsigned)f2bf(c1.w) << 16);
  ((uint4*)Bt)[o * 512 + i] = v;
}

// ---------------- pass 2: fused basis + GEMM, K-split into KSLICES partials ----------
// BM=BN=128, BK=64, 4 waves (2x2), wave tile 64x64. blockIdx.z = K-slice.
// A-tile is COMPUTED in-kernel (tanh + Laguerre) from the x panel, never materialized.
__global__ __launch_bounds__(256) void gemm_fused(const float* __restrict__ x,
                                                  const unsigned short* __restrict__ Bt,
                                                  float* __restrict__ P) {
  __shared__ unsigned short As[128 * LDT];
  __shared__ unsigned short Bs[128 * LDT];

  const int tid  = threadIdx.x;
  const int lane = tid & 63;
  const int wave = tid >> 6;
  const int wm = wave >> 1, wn = wave & 1;
  const int bn = blockIdx.x * 128;   // 4 n-blocks
  const int bm = blockIdx.y * 128;   // 64 m-blocks
  const int z  = blockIdx.z;         // 4 K-slices
  const int kbase = z * NT_SLICE;    // K-tile index base

  // A staging: each thread owns one float4 of x (row ar, 4 i-values at half ah)
  const int ar = tid >> 1, ah = tid & 1;
  // B staging: each thread stages 4 uint4 rows (r0 + j*32)
  const int r0 = tid >> 3, c8 = tid & 7;

  const float4* xg = (const float4*)x;       // row stride 128 float4
  const uint4*  Bg = (const uint4*)Bt;       // row stride 512 chunks

  float4 xa = xg[(size_t)(bm + ar) * 128 + kbase * 2 + ah];
  uint4 rb[4];
#pragma unroll
  for (int j = 0; j < 4; ++j)
    rb[j] = Bg[(size_t)(bn + r0 + j * 32) * 512 + kbase * 8 + c8];

  f32x4 zero = {0.f, 0.f, 0.f, 0.f};
  f32x4 acc[4][4];
#pragma unroll
  for (int mi = 0; mi < 4; ++mi)
#pragma unroll
    for (int ni = 0; ni < 4; ++ni) acc[mi][ni] = zero;

  const int arow = (lane & 15);
  const int kgrp = (lane >> 4) * 8;

  for (int kt = 0; kt < NT_SLICE; ++kt) {
    __syncthreads();   // previous compute done, LDS reusable
    // ---- A: basis -> LDS (4 independent tanh/recurrence chains) ----
    {
      float xv[4] = {xa.x, xa.y, xa.z, xa.w};
#pragma unroll
      for (int q = 0; q < 4; ++q)
        *(uint4*)&As[ar * LDT + (ah * 4 + q) * 8] = basis_pack(xv[q]);
    }
    // ---- B: regs -> LDS ----
#pragma unroll
    for (int j = 0; j < 4; ++j)
      *(uint4*)&Bs[(r0 + j * 32) * LDT + c8 * 8] = rb[j];
    __syncthreads();   // LDS ready

    if (kt + 1 < NT_SLICE) {   // prefetch next tile into regs
      xa = xg[(size_t)(bm + ar) * 128 + (kbase + kt + 1) * 2 + ah];
#pragma unroll
      for (int j = 0; j < 4; ++j)
        rb[j] = Bg[(size_t)(bn + r0 + j * 32) * 512 + (kbase + kt + 1) * 8 + c8];
    }

#pragma unroll
    for (int ks = 0; ks < 2; ++ks) {
      bf16x8 af[4], bfr[4];
#pragma unroll
      for (int mi = 0; mi < 4; ++mi)
        af[mi] = *(const bf16x8*)&As[(wm * 64 + mi * 16 + arow) * LDT + ks * 32 + kgrp];
#pragma unroll
      for (int ni = 0; ni < 4; ++ni)
        bfr[ni] = *(const bf16x8*)&Bs[(wn * 64 + ni * 16 + arow) * LDT + ks * 32 + kgrp];
#pragma unroll
      for (int mi = 0; mi < 4; ++mi)
#pragma unroll
        for (int ni = 0; ni < 4; ++ni)
          acc[mi][ni] = __builtin_amdgcn_mfma_f32_16x16x32_bf16(af[mi], bfr[ni], acc[mi][ni], 0, 0, 0);
    }
  }

  // epilogue -> partials P[z][row][col]; C/D layout: col=lane&15, row=(lane>>4)*4+r
  float* Pz = P + (size_t)z * B_ROWS * OUT_DIM;
#pragma unroll
  for (int mi = 0; mi < 4; ++mi) {
    int row = bm + wm * 64 + mi * 16 + ((lane >> 4) << 2);
#pragma unroll
    for (int ni = 0; ni < 4; ++ni) {
      int col = bn + wn * 64 + ni * 16 + (lane & 15);
#pragma unroll
      for (int r = 0; r < 4; ++r)
        Pz[(size_t)(row + r) * 512 + col] = acc[mi][ni][r];
    }
  }
}

// ---------------- pass 3: out = sum of KSLICES partials (float4-vectorized) ------
__global__ void reduce_kernel(const float* __restrict__ P, float* __restrict__ out) {
  const size_t i = (size_t)blockIdx.x * 256 + threadIdx.x;  // float4 index
  const float4* p = (const float4*)P;
  const size_t stride = (size_t)B_ROWS * OUT_DIM / 4;       // 1048576
  float4 a = p[i];
#pragma unroll
  for (int s = 1; s < KSLICES; ++s) {
    float4 b = p[i + (size_t)s * stride];
    a.x += b.x; a.y += b.y; a.z += b.z; a.w += b.w;
  }
  ((float4*)out)[i] = a;
}

// ---------------- fallback (ws too small): direct f32, correct but slow ----------------
__global__ void naive_kernel(const float* __restrict__ x, const float* __restrict__ c,
                             float* __restrict__ out) {
  __shared__ float bas[IN_DIM * NDEG];   // 16 KB
  int b = blockIdx.x;
  for (int i = threadIdx.x; i < IN_DIM; i += 256) {
    float t = tanhf(x[(size_t)b * IN_DIM + i]);
    float L[NDEG];
    laguerre8(t, L);
#pragma unroll
    for (int d = 0; d < NDEG; ++d) bas[i * NDEG + d] = L[d];
  }
  __syncthreads();
  for (int o = threadIdx.x; o < OUT_DIM; o += 256) {
    float acc = 0.f;
    for (int i = 0; i < IN_DIM; ++i) {
      const float* cp = c + ((size_t)i * OUT_DIM + o) * NDEG;
#pragma unroll
    for (int d = 0; d < NDEG; ++d) acc += bas[i * NDEG + d] * cp[d];
    }
    out[(size_t)b * OUT_DIM + o] = acc;
  }
}

extern "C" void kernel_launch(void* const* d_in, const int* in_sizes, int n_in,
                              void* d_out, int out_size, void* d_ws, size_t ws_size,
                              hipStream_t stream) {
  const float* x    = (const float*)d_in[0];
  const float* coef = (const float*)d_in[1];
  float* out = (float*)d_out;

  const size_t P_BYTES  = (size_t)KSLICES * B_ROWS * OUT_DIM * 4;  // 64 MiB
  const size_t BT_BYTES = (size_t)OUT_DIM * KDIM * 2;              // 4 MiB

  if (ws_size >= P_BYTES + BT_BYTES) {   // 68 MiB — proven available in round 1
    float* Pp = (float*)d_ws;
    unsigned short* Bt = (unsigned short*)((char*)d_ws + P_BYTES);
    coeff_kernel<<<(IN_DIM * OUT_DIM) / 256, 256, 0, stream>>>(coef, Bt);
    dim3 grid(OUT_DIM / 128, B_ROWS / 128, KSLICES);   // (4, 64, 4) = 1024 blocks
    gemm_fused<<<grid, 256, 0, stream>>>(x, Bt, Pp);
    reduce_kernel<<<(B_ROWS * OUT_DIM / 4) / 256, 256, 0, stream>>>(Pp, out);
  } else {
    naive_kernel<<<B_ROWS, 256, 0, stream>>>(x, coef, out);
  }
}

// Round 3
// 73.215 us; speedup vs baseline: 2.7795x; 1.6451x over previous
//
#include <hip/hip_runtime.h>

#define B_ROWS 8192
#define IN_DIM 512
#define OUT_DIM 512
#define NDEG 8                 // DEGREE+1
#define KDIM (IN_DIM * NDEG)   // 4096
#define ZSLICES 4
#define NKT 16                 // K-steps (of 64) per z-slice
#define BM 256
#define BN 128
#define LDB 72                 // padded B LDS stride (shorts)

typedef short bf16x8 __attribute__((ext_vector_type(8)));
typedef float f32x4  __attribute__((ext_vector_type(4)));

__device__ __forceinline__ unsigned short f2bf(float f) {
  unsigned u = __float_as_uint(f);
  u += 0x7fffu + ((u >> 16) & 1u);   // RNE
  return (unsigned short)(u >> 16);
}

__device__ __forceinline__ void laguerre8(float t, float* L) {
  L[0] = 1.0f;
  L[1] = 1.5f - t;
#pragma unroll
  for (int k = 2; k < NDEG; ++k)
    L[k] = ((2.0f * (float)k - 0.5f - t) * L[k - 1] -
            ((float)k - 0.5f) * L[k - 2]) * (1.0f / (float)k);
}

// ---- pass 1: A in tile-major pre-swizzled layout --------------------------------
// chunk(16B) index = (mtile*64 + ktile)*2048 + r*8 + (c ^ (r&7));  r=b%256, c=i%8
__global__ void basis_kernel(const float* __restrict__ x, unsigned short* __restrict__ A) {
  int idx = blockIdx.x * 256 + threadIdx.x;
  int b = idx >> 9, i = idx & 511;
  float L[NDEG];
  laguerre8(tanhf(x[idx]), L);
  uint4 v;
  v.x = (unsigned)f2bf(L[0]) | ((unsigned)f2bf(L[1]) << 16);
  v.y = (unsigned)f2bf(L[2]) | ((unsigned)f2bf(L[3]) << 16);
  v.z = (unsigned)f2bf(L[4]) | ((unsigned)f2bf(L[5]) << 16);
  v.w = (unsigned)f2bf(L[6]) | ((unsigned)f2bf(L[7]) << 16);
  int T = b >> 8, r = b & 255, kt = i >> 3, c = i & 7;
  size_t chunk = ((size_t)(T * 64 + kt)) * 2048 + r * 8 + (c ^ (r & 7));
  ((uint4*)A)[chunk] = v;
}

// ---- pass 2: Bt[o][i] chunks, linear --------------------------------------------
__global__ void coeff_kernel(const float* __restrict__ c, unsigned short* __restrict__ Bt) {
  int idx = blockIdx.x * 256 + threadIdx.x;   // i*512 + o
  int i = idx >> 9, o = idx & 511;
  const float4* cp = (const float4*)(c + (size_t)idx * 8);
  float4 c0 = cp[0], c1 = cp[1];
  uint4 v;
  v.x = (unsigned)f2bf(c0.x) | ((unsigned)f2bf(c0.y) << 16);
  v.y = (unsigned)f2bf(c0.z) | ((unsigned)f2bf(c0.w) << 16);
  v.z = (unsigned)f2bf(c1.x) | ((unsigned)f2bf(c1.y) << 16);
  v.w = (unsigned)f2bf(c1.z) | ((unsigned)f2bf(c1.w) << 16);
  ((uint4*)Bt)[o * 512 + i] = v;
}

// ---- pass 3: GEMM. A via global_load_lds (pre-swizzled), B via padded LDS. ------
__global__ __launch_bounds__(512, 4) void gemm_kernel(const unsigned short* __restrict__ A,
                                                      const unsigned short* __restrict__ Bt,
                                                      unsigned short* __restrict__ P) {
  __shared__ unsigned short lds[32768];   // 64 KB: As = 16384 shorts, Bs = 9216 shorts
  unsigned short* As = lds;
  unsigned short* Bs = lds + 16384;

  const int tid = threadIdx.x;
  const int lane = tid & 63;
  const int w = tid >> 6;
  const int wm = w >> 1, wn = w & 1;

  // XCD-aware decode: xcd owns (z = xcd>>1, y-half = xcd&1); A/B panels fetched once/XCD
  const int g = blockIdx.x;                 // 0..511
  const int xcd = g & 7, idx = g >> 3;      // 64 slots per xcd
  const int z = xcd >> 1;
  const int y = (xcd & 1) * 16 + (idx & 15);   // m-tile 0..31
  const int bn = (idx >> 4) * BN;              // n-block col base

  const uint4* Ag = (const uint4*)A;
  const uint4* Bg = (const uint4*)Bt;
  const size_t tile0 = ((size_t)(y * 64 + z * NKT)) * 2048;   // chunk base, kt=0

  // B staging: thread -> row rB, chunk pair cB
  const int rB = tid >> 2, cB = (tid & 3) * 2;
  uint4 rb0 = Bg[(size_t)(bn + rB) * 512 + z * NKT * 8 + cB];
  uint4 rb1 = Bg[(size_t)(bn + rB) * 512 + z * NKT * 8 + cB + 1];

  // fragment addressing
  const int arow = lane & 15, hi = lane >> 4;
  const int swz0 = hi ^ (arow & 7);          // chunk for ks=0
  const unsigned short* a0 = As + (wm * 64 + arow) * 64 + swz0 * 8;
  const unsigned short* a1 = As + (wm * 64 + arow) * 64 + (swz0 ^ 4) * 8;
  const unsigned short* bb = Bs + (wn * 64 + arow) * LDB;

  f32x4 zero = {0.f, 0.f, 0.f, 0.f};
  f32x4 acc[4][4];
#pragma unroll
  for (int mi = 0; mi < 4; ++mi)
#pragma unroll
    for (int ni = 0; ni < 4; ++ni) acc[mi][ni] = zero;

  for (int kt = 0; kt < NKT; ++kt) {
    __syncthreads();   // previous reads done; LDS free
    // A: 4 global_load_lds (wave-uniform LDS base, per-lane global src)
    {
      size_t base = tile0 + (size_t)kt * 2048 + w * 256;
#pragma unroll
      for (int j = 0; j < 4; ++j) {
        const uint4* gp = Ag + base + j * 64 + lane;
        __builtin_amdgcn_global_load_lds(
            (const __attribute__((address_space(1))) unsigned int*)gp,
            (__attribute__((address_space(3))) unsigned int*)(As + (w * 256 + j * 64) * 8),
            16, 0, 0);
      }
    }
    // B: regs -> padded LDS
    *(uint4*)&Bs[rB * LDB + cB * 8] = rb0;
    *(uint4*)&Bs[rB * LDB + (cB + 1) * 8] = rb1;
    __syncthreads();   // drains vmcnt+lgkm; tile ready

    if (kt + 1 < NKT) {   // prefetch next B tile into regs
      rb0 = Bg[(size_t)(bn + rB) * 512 + (z * NKT + kt + 1) * 8 + cB];
      rb1 = Bg[(size_t)(bn + rB) * 512 + (z * NKT + kt + 1) * 8 + cB + 1];
    }

#pragma unroll
    for (int ks = 0; ks < 2; ++ks) {
      const unsigned short* ap = ks ? a1 : a0;
      bf16x8 af[4], bfr[4];
#pragma unroll
      for (int mi = 0; mi < 4; ++mi)
        af[mi] = *(const bf16x8*)(ap + mi * 1024);          // +16 rows = 1024 shorts
#pragma unroll
      for (int ni = 0; ni < 4; ++ni)
        bfr[ni] = *(const bf16x8*)(bb + ni * 16 * LDB + ks * 32 + hi * 8);
#pragma unroll
      for (int mi = 0; mi < 4; ++mi)
#pragma unroll
        for (int ni = 0; ni < 4; ++ni)
          acc[mi][ni] = __builtin_amdgcn_mfma_f32_16x16x32_bf16(af[mi], bfr[ni], acc[mi][ni], 0, 0, 0);
    }
  }

  // ---- epilogue: bf16 via per-wave LDS bounce -> full-line uint4 stores ----
  __syncthreads();                       // all compute reads done; reuse lds
  unsigned short* W = lds + w * 4096;    // 8 KB per wave: 64 rows x 64 shorts, swizzled
#pragma unroll
  for (int mi = 0; mi < 4; ++mi)
#pragma unroll
    for (int ni = 0; ni < 4; ++ni) {
      int col = ni * 16 + arow;
      int c8 = col >> 3, cpos = col & 7;
#pragma unroll
      for (int r = 0; r < 4; ++r) {
        int row = mi * 16 + hi * 4 + r;
        W[row * 64 + ((c8 ^ (row & 7)) << 3) + cpos] = f2bf(acc[mi][ni][r]);
      }
    }
  // wave reads its own region: no barrier needed
  const int rr = lane >> 3, cc = lane & 7;
#pragma unroll
  for (int it = 0; it < 8; ++it) {
    int row = it * 8 + rr;
    uint4 v = *(uint4*)&W[row * 64 + ((cc ^ (row & 7)) << 3)];
    size_t pr = ((size_t)z * B_ROWS + (y * 256 + wm * 64 + row)) * 512 + bn + wn * 64 + cc * 8;
    *(uint4*)&P[pr] = v;   // 8 lanes = one full 128B line
  }
}

// ---- pass 4: out = sum of bf16 partials, f32 ------------------------------------
__global__ void reduce_kernel(const unsigned short* __restrict__ P, float* __restrict__ out) {
  size_t t = (size_t)blockIdx.x * 256 + threadIdx.x;   // 8-elem chunk index
  const uint4* p = (const uint4*)P;
  const size_t stride = (size_t)B_ROWS * OUT_DIM / 8;  // chunks per slice
  float s[8] = {0, 0, 0, 0, 0, 0, 0, 0};
#pragma unroll
  for (int zz = 0; zz < ZSLICES; ++zz) {
    uint4 v = p[t + zz * stride];
    unsigned q[4] = {v.x, v.y, v.z, v.w};
#pragma unroll
    for (int j = 0; j < 4; ++j) {
      s[2 * j]     += __uint_as_float((q[j] & 0xffffu) << 16);
      s[2 * j + 1] += __uint_as_float(q[j] & 0xffff0000u);
    }
  }
  float4 o0 = {s[0], s[1], s[2], s[3]}, o1 = {s[4], s[5], s[6], s[7]};
  ((float4*)out)[t * 2]     = o0;
  ((float4*)out)[t * 2 + 1] = o1;
}

// ---- fallback -------------------------------------------------------------------
__global__ void naive_kernel(const float* __restrict__ x, const float* __restrict__ c,
                             float* __restrict__ out) {
  __shared__ float bas[IN_DIM * NDEG];
  int b = blockIdx.x;
  for (int i = threadIdx.x; i < IN_DIM; i += 256) {
    float t = tanhf(x[(size_t)b * IN_DIM + i]);
    float L[NDEG];
    laguerre8(t, L);
#pragma unroll
    for (int d = 0; d < NDEG; ++d) bas[i * NDEG + d] = L[d];
  }
  __syncthreads();
  for (int o = threadIdx.x; o < OUT_DIM; o += 256) {
    float acc = 0.f;
    for (int i = 0; i < IN_DIM; ++i) {
      const float* cp = c + ((size_t)i * OUT_DIM + o) * NDEG;
#pragma unroll
      for (int d = 0; d < NDEG; ++d) acc += bas[i * NDEG + d] * cp[d];
    }
    out[(size_t)b * OUT_DIM + o] = acc;
  }
}

extern "C" void kernel_launch(void* const* d_in, const int* in_sizes, int n_in,
                              void* d_out, int out_size, void* d_ws, size_t ws_size,
                              hipStream_t stream) {
  const float* x    = (const float*)d_in[0];
  const float* coef = (const float*)d_in[1];
  float* out = (float*)d_out;

  const size_t A_BYTES  = (size_t)B_ROWS * KDIM * 2;              // 64 MiB
  const size_t P_BYTES  = (size_t)ZSLICES * B_ROWS * OUT_DIM * 2; // 32 MiB
  const size_t BT_BYTES = (size_t)OUT_DIM * KDIM * 2;             // 4 MiB
  // layout: [A 64MiB][P 32MiB... overlaps nothing][Bt]
  // A is consumed by gemm while P is written by gemm -> need disjoint: total 100 MiB?
  // ws proven >= 68 MiB only. Overlap trick: P can alias A? gemm reads A and writes P
  // concurrently -> must NOT alias. Fit check below; fallback chain handles small ws.

  if (ws_size >= A_BYTES + P_BYTES + BT_BYTES) {
    unsigned short* Abuf = (unsigned short*)d_ws;
    unsigned short* Pp   = (unsigned short*)((char*)d_ws + A_BYTES);
    unsigned short* Bt   = (unsigned short*)((char*)d_ws + A_BYTES + P_BYTES);
    basis_kernel<<<(B_ROWS * IN_DIM) / 256, 256, 0, stream>>>(x, Abuf);
    coeff_kernel<<<(IN_DIM * OUT_DIM) / 256, 256, 0, stream>>>(coef, Bt);
    gemm_kernel<<<512, 512, 0, stream>>>(Abuf, Bt, Pp);
    reduce_kernel<<<(B_ROWS * OUT_DIM / 8) / 256, 256, 0, stream>>>(Pp, out);
  } else if (ws_size >= A_BYTES + BT_BYTES) {
    // smaller ws: reuse out (f32) directly is not possible with z-split;
    // run z=1-style: not implemented -> use naive fallback only if truly tiny.
    naive_kernel<<<B_ROWS, 256, 0, stream>>>(x, coef, out);
  } else {
    naive_kernel<<<B_ROWS, 256, 0, stream>>>(x, coef, out);
  }
}